// Round 10
// baseline (145.728 us; speedup 1.0000x reference)
//
#include <hip/hip_runtime.h>
#include <cstdint>

#define BATCHES 8
#define NPTS 2048
#define NF 512
#define KNN 32
#define WAVES 8
#define FCH 16              // features per chunk -> slab = 2048 x 16 f32 = 128 KB LDS
#define NCHUNK (NF / FCH)   // 32 chunk-blocks per batch

// R10 = R9 resubmitted verbatim (R9 bench was an infra failure, like R2; kernel
// audited: no spin/hang paths, all LDS/global indices bounded, 128 KB static
// LDS legal on gfx950).
// R9 design: select unchanged (R8, proven ~24us). Gather rebuilt as FEATURE-SLAB
// LDS: R8 exposed gather = 48us at 22 TB/s L2 (64% of ceiling, no L1 reuse).
// Each x-row is read ~32x (once per list containing it) -> move that reuse into
// LDS: block (b,c) stages x[b][:, c*16..) = 128 KB once (x read ONCE chip-wide,
// 32 MB), then serves all 2048 queries for those 16 features from LDS.
// L2/HBM gather traffic 1 GiB -> ~34 MB; cost becomes 4 MB LDS reads per CU
// (~7-15us at 112-256 B/cy) + reduce overhead. Wave: 4 queries/pass, lane =
// (q=lane>>4, sub=(lane>>2)&3, f4=lane&3); 8 independent ds_read_b128/pass;
// neighbor int4s prefetched 1 pass ahead (lane-varying, no broadcasts);
// 2-round shfl_xor reduce over sub; sub==0 lanes nt-store 64 B/query.
// grid 256 = 1 block/CU (128 KB LDS). Tripwire: gather > 40us => model wrong
// (check SQ_LDS_BANK_CONFLICT first).

typedef float vfloat4 __attribute__((ext_vector_type(4)));  // native vec for nt-store

// ======================= PHASE 1: select (R8 verbatim) =======================
__global__ __launch_bounds__(512, 4)
void knn_select(const float* __restrict__ points,
                int* __restrict__ lists) {
    __shared__ __align__(16) float    pts4[NPTS * 4];     // [N][4]: one b128/candidate
    __shared__ __align__(16) uint64_t ckey[WAVES][64];    // compact keys (fast path)
    __shared__ __align__(16) int      tiebuf[WAVES][KNN]; // tie-fallback emit

    const int tid  = threadIdx.x;
    const int lane = tid & 63;
    const int w    = tid >> 6;

    const int b  = blockIdx.x & 7;
    const int pr = blockIdx.x >> 3;          // [0,256) octet within batch
    const int lq = pr * 8 + w;               // this wave's query (one, straight-line)

    {   // stage points[b] into LDS as [N][4] (pad .w)
        const float* src = points + (size_t)b * NPTS * 3;
        for (int p = tid; p < NPTS; p += 512) {
            float4* d = (float4*)&pts4[p * 4];
            *d = make_float4(src[p * 3 + 0], src[p * 3 + 1], src[p * 3 + 2], 0.f);
        }
    }
    __syncthreads();

    const uint64_t lmlt = (1ull << lane) - 1ull;
    const float4   qp   = *(const float4*)&pts4[lq * 4];

    // ---- distances in registers (R0/R1 proven no-spill shape) ----
    uint32_t db[32];
    #pragma unroll
    for (int j = 0; j < 32; ++j) {
        const int n = lane + (j << 6);
        const float4 pp = *(const float4*)&pts4[n * 4];
        const float dx = qp.x - pp.x;
        const float dy = qp.y - pp.y;
        const float dz = qp.z - pp.z;
        db[j] = __float_as_uint(dx * dx + dy * dy + dz * dz);
    }

    auto countLE = [&](uint32_t t) -> uint32_t {
        uint32_t c = 0;
        #pragma unroll
        for (int j = 0; j < 32; ++j)
            c += (uint32_t)__builtin_popcountll(__ballot(db[j] <= t));
        return c;
    };

    auto compactSelect = [&](uint32_t thr, uint32_t cthr) -> int {
        uint32_t base = 0;
        #pragma unroll
        for (int j = 0; j < 32; ++j) {
            const bool     p = db[j] <= thr;
            const uint64_t m = __ballot(p);
            if (p) {
                const int slot = (int)base + (int)__popcll(m & lmlt);
                ckey[w][slot] = (((uint64_t)db[j]) << 11) | (uint64_t)(lane + (j << 6));
            }
            base += (uint32_t)__builtin_popcountll(m);
        }
        uint64_t key = (lane < (int)cthr) ? ckey[w][lane] : ~0ull;
        #pragma unroll
        for (int k = 2; k <= 32; k <<= 1) {
            #pragma unroll
            for (int j = k >> 1; j > 0; j >>= 1) {
                const uint64_t other = __shfl_xor((unsigned long long)key, j);
                const bool takeMin = (((lane & j) == 0) == ((lane & k) == 0));
                key = ((key < other) == takeMin) ? key : other;
            }
        }
        {
            const uint64_t other = __shfl_xor((unsigned long long)key, 32);
            const uint64_t mn = key < other ? key : other;
            const uint64_t mx = key < other ? other : key;
            key = ((lane & 32) == 0) ? mn : mx;
        }
        return (int)(key & 0x7FFull);
    };

    auto tieFallback = [&](uint32_t T, int cnt_lt) -> int {
        int base_lt = 0, base_eq = 0;
        #pragma unroll
        for (int j = 0; j < 32; ++j) {
            const bool lt = db[j] < T;
            const bool eq = db[j] == T;
            const uint64_t mlt = __ballot(lt);
            const uint64_t meq = __ballot(eq);
            int slot = -1;
            if (lt)      slot = base_lt + (int)__popcll(mlt & lmlt);
            else if (eq) slot = cnt_lt + base_eq + (int)__popcll(meq & lmlt);
            if (slot >= 0 && slot < KNN) tiebuf[w][slot] = lane + (j << 6);
            base_lt += (int)__popcll(mlt);
            base_eq += (int)__popcll(meq);
        }
        return tiebuf[w][lane & (KNN - 1)];
    };

    int selv;
    {   // per-lane min + 21-round bitonic sort of 64 minima -> probe
        uint32_t lmin = db[0];
        #pragma unroll
        for (int j = 1; j < 32; ++j) lmin = min(lmin, db[j]);
        uint32_t sm = lmin;
        #pragma unroll
        for (int k = 2; k <= 64; k <<= 1) {
            #pragma unroll
            for (int j = k >> 1; j > 0; j >>= 1) {
                const uint32_t o  = (uint32_t)__shfl_xor((int)sm, j);
                const uint32_t mn = min(sm, o);
                const uint32_t mx = max(sm, o);
                sm = (((lane & j) == 0) == ((lane & k) == 0)) ? mn : mx;
            }
        }
        const uint32_t probe = (uint32_t)__builtin_amdgcn_readlane((int)sm, 31);
        const uint32_t hi0   = (uint32_t)__builtin_amdgcn_readlane((int)sm, 63);

        const uint32_t c1 = countLE(probe);            // >= 32 guaranteed
        if (c1 <= 64u) selv = compactSelect(probe, c1);
        else {
            const uint32_t cs = countLE(hi0);          // >= 64 guaranteed
            if (cs <= 64u) selv = compactSelect(hi0, cs);
            else if (probe == 0u) selv = tieFallback(0u, 0);
            else {
                uint32_t lo = 0u, hi = probe;          // c(lo)<32 (self), c(hi)>64
                bool done = false;
                while (!done && hi - lo > 1u) {
                    const uint32_t mid = lo + ((hi - lo) >> 1);
                    const uint32_t c   = countLE(mid);
                    if (c >= KNN && c <= 64u) { selv = compactSelect(mid, c); done = true; }
                    else if (c > 64u) hi = mid; else lo = mid;
                }
                if (!done) selv = tieFallback(hi, (int)countLE(lo));
            }
        }
    }

    if (lane < KNN) lists[((size_t)b * NPTS + lq) * KNN + lane] = selv;
}

// =============== PHASE 2: feature-slab LDS gather + max-pool ===============
__global__ __launch_bounds__(512)
void knn_gather(const float* __restrict__ x,
                const int* __restrict__ lists,
                float* __restrict__ out) {
    __shared__ __align__(16) float slab[NPTS * FCH];   // 128 KB: [2048][16] f32

    const int tid  = threadIdx.x;
    const int lane = tid & 63;
    const int w    = tid >> 6;

    const int b = blockIdx.x & 7;        // XCD-affine batch
    const int c = blockIdx.x >> 3;       // feature chunk [0,32)

    const float* xb = x + (size_t)b * NPTS * NF + c * FCH;

    // ---- stage slab: each thread 16 float4s; 64 B global segments, LDS
    // writes contiguous (conflict-free) ----
    #pragma unroll
    for (int it = 0; it < (NPTS * FCH / 4) / 512; ++it) {   // 16 iterations
        const int t  = it * 512 + tid;
        const int r  = t >> 2;
        const int f4 = t & 3;
        const float4 v = *(const float4*)(xb + (size_t)r * NF + f4 * 4);
        ((float4*)slab)[r * 4 + f4] = v;
    }
    __syncthreads();

    const int q   = lane >> 4;           // 0..3  query within pass
    const int sub = (lane >> 2) & 3;     // 0..3  neighbor octet
    const int f4  = lane & 3;            // 0..3  float4 within 16-feature chunk

    const int  qw    = w * (NPTS / WAVES);                  // 256 queries/wave
    const int* lbase = lists + (size_t)b * NPTS * KNN;

    // prefetch pass 0 neighbor ints (8 per lane, lane-varying: no broadcasts)
    int4 curA, curB;
    {
        const int4* lp = (const int4*)(lbase + (size_t)(qw + q) * KNN + sub * 8);
        curA = lp[0];
        curB = lp[1];
    }

    #pragma unroll 2
    for (int p = 0; p < NPTS / WAVES / 4; ++p) {            // 64 passes
        // issue next pass's list loads (wrap at end: redundant, branch-free)
        int4 nxtA, nxtB;
        {
            const int pn = (p + 1) & 63;
            const int4* lp = (const int4*)(lbase + (size_t)(qw + pn * 4 + q) * KNN + sub * 8);
            nxtA = lp[0];
            nxtB = lp[1];
        }

        const int qi = qw + p * 4 + q;

        // ---- 8 independent ds_read_b128 + in-lane tree max ----
        const float4* sl = (const float4*)slab;
        const float4 v0 = sl[(curA.x & (NPTS - 1)) * 4 + f4];
        const float4 v1 = sl[(curA.y & (NPTS - 1)) * 4 + f4];
        const float4 v2 = sl[(curA.z & (NPTS - 1)) * 4 + f4];
        const float4 v3 = sl[(curA.w & (NPTS - 1)) * 4 + f4];
        const float4 v4 = sl[(curB.x & (NPTS - 1)) * 4 + f4];
        const float4 v5 = sl[(curB.y & (NPTS - 1)) * 4 + f4];
        const float4 v6 = sl[(curB.z & (NPTS - 1)) * 4 + f4];
        const float4 v7 = sl[(curB.w & (NPTS - 1)) * 4 + f4];

        float4 acc;
        acc.x = fmaxf(fmaxf(fmaxf(v0.x, v1.x), fmaxf(v2.x, v3.x)),
                      fmaxf(fmaxf(v4.x, v5.x), fmaxf(v6.x, v7.x)));
        acc.y = fmaxf(fmaxf(fmaxf(v0.y, v1.y), fmaxf(v2.y, v3.y)),
                      fmaxf(fmaxf(v4.y, v5.y), fmaxf(v6.y, v7.y)));
        acc.z = fmaxf(fmaxf(fmaxf(v0.z, v1.z), fmaxf(v2.z, v3.z)),
                      fmaxf(fmaxf(v4.z, v5.z), fmaxf(v6.z, v7.z)));
        acc.w = fmaxf(fmaxf(fmaxf(v0.w, v1.w), fmaxf(v2.w, v3.w)),
                      fmaxf(fmaxf(v4.w, v5.w), fmaxf(v6.w, v7.w)));

        // ---- reduce over the 4 sub-lanes (strides 4, 8) ----
        acc.x = fmaxf(acc.x, __shfl_xor(acc.x, 4));
        acc.y = fmaxf(acc.y, __shfl_xor(acc.y, 4));
        acc.z = fmaxf(acc.z, __shfl_xor(acc.z, 4));
        acc.w = fmaxf(acc.w, __shfl_xor(acc.w, 4));
        acc.x = fmaxf(acc.x, __shfl_xor(acc.x, 8));
        acc.y = fmaxf(acc.y, __shfl_xor(acc.y, 8));
        acc.z = fmaxf(acc.z, __shfl_xor(acc.z, 8));
        acc.w = fmaxf(acc.w, __shfl_xor(acc.w, 8));

        if (sub == 0) {   // 4 lanes/query write its 16 chunk-features (64 B)
            vfloat4* o = (vfloat4*)(out + ((size_t)b * NPTS + qi) * NF + c * FCH + f4 * 4);
            __builtin_nontemporal_store(vfloat4{acc.x, acc.y, acc.z, acc.w}, o);
        }

        curA = nxtA;
        curB = nxtB;
    }
}

extern "C" void kernel_launch(void* const* d_in, const int* in_sizes, int n_in,
                              void* d_out, int out_size, void* d_ws, size_t ws_size,
                              hipStream_t stream) {
    const float* x      = (const float*)d_in[0];   // [8, 2048, 512] f32
    const float* points = (const float*)d_in[1];   // [8, 2048, 3]   f32
    float* out          = (float*)d_out;           // [8, 2048, 512] f32
    int*   lists        = (int*)d_ws;              // 16384 x 32 int = 2 MB

    knn_select<<<dim3(BATCHES * (NPTS / WAVES)), dim3(512), 0, stream>>>(points, lists);
    knn_gather<<<dim3(BATCHES * NCHUNK), dim3(512), 0, stream>>>(x, lists, out);
}